// Round 3
// baseline (192.019 us; speedup 1.0000x reference)
//
#include <hip/hip_runtime.h>
#include <hip/hip_bf16.h>

#define D_MODEL 1024
#define NHEAD   16
#define HDIM    64
#define SEQQ    2048
#define NBATCH  2
#define MROWS   (NBATCH * SEQQ)   // 4096

typedef unsigned short u16;
typedef __attribute__((ext_vector_type(8))) short short8;   // 8 bf16 (4 VGPRs)
typedef __attribute__((ext_vector_type(4))) short bf16x4;   // 4 bf16 (2 VGPRs)
typedef __attribute__((ext_vector_type(4))) float floatx4;  // 4 fp32 acc

__device__ __forceinline__ u16 f2b(float f) {
    union { __hip_bfloat16 h; u16 u; } cv;
    cv.h = __float2bfloat16(f);
    return cv.u;
}
__device__ __forceinline__ float b2f(u16 u) {
    return __uint_as_float(((unsigned int)u) << 16);
}
__device__ __forceinline__ short8 load8(const u16* p) {
    return *reinterpret_cast<const short8*>(p);
}
__device__ __forceinline__ bf16x4 load4v(const u16* p) {
    return *reinterpret_cast<const bf16x4*>(p);
}
__device__ __forceinline__ unsigned pack2(float lo, float hi) {
    return ((unsigned)f2b(hi) << 16) | (unsigned)f2b(lo);
}
__device__ __forceinline__ void async_cp16(const void* g, void* l) {
    __builtin_amdgcn_global_load_lds(
        (const __attribute__((address_space(1))) void*)g,
        (__attribute__((address_space(3))) void*)l, 16, 0, 0);
}

// ---------------- fp32 -> bf16 convert: X (4 quarters) + 4 weights, one dispatch ----------------
__global__ void cvt_all(const float* __restrict__ X,
                        const float* __restrict__ w0, const float* __restrict__ w1,
                        const float* __restrict__ w2, const float* __restrict__ w3,
                        u16* __restrict__ xo,
                        u16* __restrict__ o0, u16* __restrict__ o1,
                        u16* __restrict__ o2, u16* __restrict__ o3) {
    const int z = blockIdx.y;
    const int n4 = (D_MODEL * D_MODEL) / 4;
    const float* in;
    u16* out;
    if (z < 4) { in = X + (size_t)z * n4 * 4;  out = xo + (size_t)z * n4 * 4; }
    else {
        in  = (z == 4) ? w0 : (z == 5) ? w1 : (z == 6) ? w2 : w3;
        out = (z == 4) ? o0 : (z == 5) ? o1 : (z == 6) ? o2 : o3;
    }
    const int i = blockIdx.x * 256 + threadIdx.x;
    float4 v = reinterpret_cast<const float4*>(in)[i];
    ushort4 o;
    o.x = f2b(v.x); o.y = f2b(v.y); o.z = f2b(v.z); o.w = f2b(v.w);
    reinterpret_cast<ushort4*>(out)[i] = o;
}

// ---------------- GEMM: C = A(MxK) * Bt(NxK)^T, m97-style 128x128 tile ----------------
__global__ __launch_bounds__(256) void gemm_qkv(
    const u16* __restrict__ A,
    const u16* __restrict__ B0, const u16* __restrict__ B1, const u16* __restrict__ B2,
    u16* __restrict__ C0, u16* __restrict__ C1, u16* __restrict__ C2)
{
    const int K = D_MODEL, N = D_MODEL;
    const u16* Bt = (blockIdx.z == 0) ? B0 : (blockIdx.z == 1 ? B1 : B2);
    u16*       Cp = (blockIdx.z == 0) ? C0 : (blockIdx.z == 1 ? C1 : C2);

    __shared__ __attribute__((aligned(16))) u16 As[128 * 32];
    __shared__ __attribute__((aligned(16))) u16 Bs[128 * 32];

    const int tid  = threadIdx.x;
    const int w    = tid >> 6;
    const int lane = tid & 63;
    const int l15  = lane & 15;
    const int quad = lane >> 4;
    const int wm   = w >> 1, wn = w & 1;
    const int tm   = blockIdx.x * 128, tn = blockIdx.y * 128;

    floatx4 acc[4][4];
#pragma unroll
    for (int i = 0; i < 4; i++)
#pragma unroll
        for (int j = 0; j < 4; j++) {
            floatx4 z = {0.f, 0.f, 0.f, 0.f};
            acc[i][j] = z;
        }

    const int srow = lane >> 2;
    const int scol = (lane & 3) * 8;

    for (int k0 = 0; k0 < K; k0 += 32) {
#pragma unroll
        for (int ch = w; ch < 8; ch += 4) {
            async_cp16(A  + (size_t)(tm + ch * 16 + srow) * K + k0 + scol, &As[ch * 512]);
            async_cp16(Bt + (size_t)(tn + ch * 16 + srow) * K + k0 + scol, &Bs[ch * 512]);
        }
        __syncthreads();

        short8 af[4], bfr[4];
#pragma unroll
        for (int mi = 0; mi < 4; mi++)
            af[mi] = load8(&As[(wm * 64 + mi * 16 + l15) * 32 + quad * 8]);
#pragma unroll
        for (int ni = 0; ni < 4; ni++)
            bfr[ni] = load8(&Bs[(wn * 64 + ni * 16 + l15) * 32 + quad * 8]);
#pragma unroll
        for (int mi = 0; mi < 4; mi++)
#pragma unroll
            for (int ni = 0; ni < 4; ni++)
                acc[mi][ni] = __builtin_amdgcn_mfma_f32_16x16x32_bf16(af[mi], bfr[ni], acc[mi][ni], 0, 0, 0);
        __syncthreads();
    }

#pragma unroll
    for (int mi = 0; mi < 4; mi++)
#pragma unroll
        for (int ni = 0; ni < 4; ni++)
#pragma unroll
            for (int rg = 0; rg < 4; rg++) {
                int row = tm + wm * 64 + mi * 16 + quad * 4 + rg;
                int col = tn + wn * 64 + ni * 16 + l15;
                Cp[(size_t)row * N + col] = f2b(acc[mi][ni][rg]);
            }
}

// ---------------- RoPE + [b,s,h,d] -> [b,h,s,d] transpose ----------------
// Q pre-scaled by (1/sqrt(HDIM)) * log2(e) so attn can use exp2 directly.
__global__ void rope_qk(const u16* __restrict__ Qraw, const u16* __restrict__ Kraw,
                        const int* __restrict__ pos, u16* __restrict__ Qt, u16* __restrict__ Kt)
{
    const int gid = blockIdx.x * 256 + threadIdx.x;
    const int j = gid & 31;
    const int s = (gid >> 5) & (SEQQ - 1);
    const int h = (gid >> 16) & (NHEAD - 1);
    const int b = gid >> 20;

    const float p   = (float)pos[s];
    const float inv = expf(-(float)j * (9.210340371976184f / 32.0f));
    float sn, cs;
    sincosf(p * inv, &sn, &cs);

    const size_t ioff = ((size_t)(b * SEQQ + s)) * D_MODEL + h * HDIM + 2 * j;
    const ushort2 qp = *reinterpret_cast<const ushort2*>(&Qraw[ioff]);
    const ushort2 kp = *reinterpret_cast<const ushort2*>(&Kraw[ioff]);
    const float qe = b2f(qp.x), qo = b2f(qp.y);
    const float ke = b2f(kp.x), ko = b2f(kp.y);

    const size_t ooff = (((size_t)(b * NHEAD + h)) * SEQQ + s) * HDIM + 2 * j;
    // 0.125 (1/sqrt(64)) * 1.4426950408889634 (log2 e)
    const float qs = 0.18033688011112042f;
    ushort2 qr;
    qr.x = f2b((qe * cs - qo * sn) * qs);
    qr.y = f2b((qe * sn + qo * cs) * qs);
    ushort2 kr;
    kr.x = f2b(ke * cs - ko * sn);
    kr.y = f2b(ke * sn + ko * cs);
    *reinterpret_cast<ushort2*>(&Qt[ooff]) = qr;
    *reinterpret_cast<ushort2*>(&Kt[ooff]) = kr;
}

// ---------------- V: [b,s,h*d] -> [b,h,d,s] transpose ----------------
__global__ __launch_bounds__(256) void vtrans(const u16* __restrict__ Vraw, u16* __restrict__ Vt)
{
    __shared__ u16 tile[64][65];
    const int s0 = blockIdx.x * 64, h = blockIdx.y, b = blockIdx.z;
    const int t = threadIdx.x;
#pragma unroll
    for (int i = 0; i < 16; i++) {
        int idx = t + i * 256;
        int sl = idx >> 6, dl = idx & 63;
        tile[sl][dl] = Vraw[((size_t)(b * SEQQ + s0 + sl)) * D_MODEL + h * HDIM + dl];
    }
    __syncthreads();
#pragma unroll
    for (int i = 0; i < 16; i++) {
        int idx = t + i * 256;
        int dl = idx >> 6, sl = idx & 63;
        Vt[(((size_t)(b * NHEAD + h)) * HDIM + dl) * SEQQ + s0 + sl] = tile[sl][dl];
    }
}

// ---------------- causal flash attention v11: swapped QK^T, in-register P ----------------
// v10 post-mortem: 3264 cy/tile-iter/CU vs ~700 cy MFMA floor. VALUBusy 27%
// (~200 VALU/wave/tile) + serial P LDS round-trip (exp -> 16 f2b -> 16
// swizzled ds_write_u16 -> lgkm -> 2 ds_read_b128) dominated.
// v11: compute S^T = mfma(Kfrag, qfrag) (operand swap; fragment loads are
// identical since A/B layouts match). Lane (l15,quad) then holds P[q=l15]
// for keys 16c+4*quad+r -- the P row is LANE-LOCAL. The MFMA k-dim is
// globally permutable if A and B agree: choose pi(slot=quad*8+4u+r) =
// key 16u+4*quad+r. Then the PV A-fragment is pure register packing
// (8 pack2 ops, no LDS, no cross-lane), and the matching V B-fragment is
// two ds_read_b64 (key groups 4*quad and 16+4*quad) from the same
// XOR-swizzled Vs. l_acc (mfma with ones) rows and O rows stay q=quad*4+r,
// so the epilogue is unchanged. exp2 with log2e folded into Q scale.
// Plds deleted: LDS = 48 KB, 2 blocks/CU.
__global__ __launch_bounds__(256, 2) void attn_kernel(
    const u16* __restrict__ Qt, const u16* __restrict__ Kt, const u16* __restrict__ Vt,
    u16* __restrict__ Out)
{
    const int bid  = blockIdx.x;
    const int slot = bid >> 3;                        // 0..63 within XCD
    const int col  = ((bid & 7) << 2) | (slot >> 4);  // (b,h) column 0..31, 4/XCD
    const int pr   = slot & 15;                       // pair index 0..15
    const int h = col & (NHEAD - 1), b = col >> 4;

    const int tid = threadIdx.x, w = tid >> 6, lane = tid & 63;
    const int l15 = lane & 15, quad = lane >> 4;
    const size_t bh = (size_t)(b * NHEAD + h);
    const u16* Qh = Qt + bh * SEQQ * HDIM;
    const u16* Kh = Kt + bh * SEQQ * HDIM;
    const u16* Vh = Vt + bh * HDIM * SEQQ;   // [d][s]

    __shared__ __attribute__((aligned(16))) u16 Ks[3][64 * 64];   // 24 KB
    __shared__ __attribute__((aligned(16))) u16 Vs[3][64 * 64];   // 24 KB

    short8 ones;
#pragma unroll
    for (int i = 0; i < 8; i++) ones[i] = (short)0x3F80;  // bf16 1.0

    // staging: each of 4 waves stages 2 K-chunks + 2 V-chunks (1 KB each)
    const int rr  = lane >> 3;                 // 0..7
    const int swz = ((lane & 7) ^ rr) * 8;     // XOR-swizzled col offset (u16)
    auto stage = [&](int buf, int tt) {
        const int k0s = tt * 64;
        async_cp16(Kh + (size_t)(k0s + w * 8 + rr) * HDIM + swz,       &Ks[buf][w * 512]);
        async_cp16(Kh + (size_t)(k0s + (w + 4) * 8 + rr) * HDIM + swz, &Ks[buf][(w + 4) * 512]);
        async_cp16(Vh + (size_t)(w * 8 + rr) * SEQQ + k0s + swz,       &Vs[buf][w * 512]);
        async_cp16(Vh + (size_t)((w + 4) * 8 + rr) * SEQQ + k0s + swz, &Vs[buf][(w + 4) * 512]);
    };

    const int s7  = l15 & 7;
    const int sw1 = ((quad)     ^ s7) * 8;     // K dims chunk 0..31
    const int sw2 = ((quad + 4) ^ s7) * 8;     // K dims chunk 32..63
    // V b64 element offsets for permuted PV k-slots (chunk*8 + (quad&1)*4):
    const int vo0 = (((quad >> 1)    ) ^ s7) * 8 + (quad & 1) * 4;  // keys  4*quad..
    const int vo1 = (((quad >> 1) + 2) ^ s7) * 8 + (quad & 1) * 4;  // keys 16+4*quad..
    const int vo2 = (((quad >> 1) + 4) ^ s7) * 8 + (quad & 1) * 4;  // keys 32+4*quad..
    const int vo3 = (((quad >> 1) + 6) ^ s7) * 8 + (quad & 1) * 4;  // keys 48+4*quad..

    for (int phase = 0; phase < 2; ++phase) {
        const int qsub  = phase ? pr : (31 - pr);  // long half first
        const int q0w   = qsub * 64 + w * 16;      // this wave's 16 q-rows
        const int tmaxp = qsub;                    // diag tile, same for all 4 waves

        if (phase) {
            // K/V buffer reuse fence: all waves done reading phase-0 tiles
            asm volatile("s_waitcnt vmcnt(0) lgkmcnt(0)" ::: "memory");
            __builtin_amdgcn_s_barrier();
        }

        // Q fragment loads FIRST (oldest vmcnt entries; drained by first wait)
        short8 qf[2];
#pragma unroll
        for (int kk = 0; kk < 2; kk++)
            qf[kk] = load8(&Qh[(size_t)(q0w + l15) * HDIM + kk * 32 + quad * 8]);

        floatx4 O[4];
        floatx4 l_acc = {0.f, 0.f, 0.f, 0.f};
#pragma unroll
        for (int c = 0; c < 4; c++) { floatx4 z = {0.f, 0.f, 0.f, 0.f}; O[c] = z; }

        stage(0, 0);
        if (tmaxp >= 1) stage(1, 1);

        for (int t = 0; t <= tmaxp; ++t) {
            // stage(t) must be complete; stage(t+1) (4 DMAs) may stay in flight
            if (t < tmaxp) asm volatile("s_waitcnt vmcnt(4)" ::: "memory");
            else           asm volatile("s_waitcnt vmcnt(0)" ::: "memory");
            __builtin_amdgcn_s_barrier();
            if (t + 2 <= tmaxp) stage((t + 2) % 3, t + 2);   // prefetch distance 2

            const u16* KsB = &Ks[t % 3][0];
            const u16* VsB = &Vs[t % 3][0];
            const int k0 = t * 64;

            // S^T[c]: rows = key_local (c*16 + quad*4 + r), cols = q (l15)
            floatx4 S[4];
#pragma unroll
            for (int c = 0; c < 4; c++) {
                const int rowb = (c * 16 + l15) * 64;
                floatx4 z = {0.f, 0.f, 0.f, 0.f};
                S[c] = __builtin_amdgcn_mfma_f32_16x16x32_bf16(load8(&KsB[rowb + sw1]), qf[0], z,    0, 0, 0);
                S[c] = __builtin_amdgcn_mfma_f32_16x16x32_bf16(load8(&KsB[rowb + sw2]), qf[1], S[c], 0, 0, 0);
            }

            if (t == tmaxp) {
                const int q = q0w + l15;
#pragma unroll
                for (int c = 0; c < 4; c++)
#pragma unroll
                    for (int r = 0; r < 4; r++)
                        if (k0 + c * 16 + quad * 4 + r > q) S[c][r] = -1e30f;
            }

#pragma unroll
            for (int c = 0; c < 4; c++)
#pragma unroll
                for (int r = 0; r < 4; r++)
                    S[c][r] = __builtin_amdgcn_exp2f(S[c][r]);

            // ---- pack P into PV A-fragments (lane-local, permuted k-slots) ----
            union { short8 v; unsigned u[4]; } pf0, pf1;
            pf0.u[0] = pack2(S[0][0], S[0][1]);
            pf0.u[1] = pack2(S[0][2], S[0][3]);
            pf0.u[2] = pack2(S[1][0], S[1][1]);
            pf0.u[3] = pack2(S[1][2], S[1][3]);
            pf1.u[0] = pack2(S[2][0], S[2][1]);
            pf1.u[1] = pack2(S[2][2], S[2][3]);
            pf1.u[2] = pack2(S[3][0], S[3][1]);
            pf1.u[3] = pack2(S[3][2], S[3][3]);

            l_acc = __builtin_amdgcn_mfma_f32_16x16x32_bf16(pf0.v, ones, l_acc, 0, 0, 0);
            l_acc = __builtin_amdgcn_mfma_f32_16x16x32_bf16(pf1.v, ones, l_acc, 0, 0, 0);

#pragma unroll
            for (int c2 = 0; c2 < 4; c2++) {
                const int rowb = (c2 * 16 + l15) * 64;
                bf16x4 a0 = load4v(&VsB[rowb + vo0]);
                bf16x4 a1 = load4v(&VsB[rowb + vo1]);
                bf16x4 a2 = load4v(&VsB[rowb + vo2]);
                bf16x4 a3 = load4v(&VsB[rowb + vo3]);
                short8 v0 = __builtin_shufflevector(a0, a1, 0, 1, 2, 3, 4, 5, 6, 7);
                short8 v1 = __builtin_shufflevector(a2, a3, 0, 1, 2, 3, 4, 5, 6, 7);
                O[c2] = __builtin_amdgcn_mfma_f32_16x16x32_bf16(pf0.v, v0, O[c2], 0, 0, 0);
                O[c2] = __builtin_amdgcn_mfma_f32_16x16x32_bf16(pf1.v, v1, O[c2], 0, 0, 0);
            }
        }

        float inv_l[4];
#pragma unroll
        for (int r = 0; r < 4; r++) inv_l[r] = 1.0f / l_acc[r];

#pragma unroll
        for (int c2 = 0; c2 < 4; c2++)
#pragma unroll
            for (int r = 0; r < 4; r++) {
                const int q    = q0w + quad * 4 + r;
                const int colo = h * HDIM + c2 * 16 + l15;
                Out[(size_t)(b * SEQQ + q) * D_MODEL + colo] = f2b(O[c2][r] * inv_l[r]);
            }
    }
}

// ---------------- o-proj GEMM: 64x128 tile (512 blocks -> 2/CU backfill) ----------------
__global__ __launch_bounds__(256) void gemm_o(
    const u16* __restrict__ A, const u16* __restrict__ Bt, float* __restrict__ C)
{
    const int K = D_MODEL, N = D_MODEL;
    __shared__ __attribute__((aligned(16))) u16 As[64 * 32];
    __shared__ __attribute__((aligned(16))) u16 Bs[128 * 32];

    const int tid  = threadIdx.x;
    const int w    = tid >> 6;
    const int lane = tid & 63;
    const int l15  = lane & 15;
    const int quad = lane >> 4;
    const int wm   = w >> 1, wn = w & 1;
    const int tm   = blockIdx.x * 64, tn = blockIdx.y * 128;

    floatx4 acc[2][4];
#pragma unroll
    for (int i = 0; i < 2; i++)
#pragma unroll
        for (int j = 0; j < 4; j++) {
            floatx4 z = {0.f, 0.f, 0.f, 0.f};
            acc[i][j] = z;
        }

    const int srow = lane >> 2;
    const int scol = (lane & 3) * 8;

    for (int k0 = 0; k0 < K; k0 += 32) {
#pragma unroll
        for (int ch = w; ch < 12; ch += 4) {
            if (ch < 4) async_cp16(A  + (size_t)(tm + ch * 16 + srow) * K + k0 + scol, &As[ch * 512]);
            else        async_cp16(Bt + (size_t)(tn + (ch - 4) * 16 + srow) * K + k0 + scol, &Bs[(ch - 4) * 512]);
        }
        __syncthreads();

        short8 af[2], bfr[4];
#pragma unroll
        for (int mi = 0; mi < 2; mi++)
            af[mi] = load8(&As[(wm * 32 + mi * 16 + l15) * 32 + quad * 8]);
#pragma unroll
        for (int ni = 0; ni < 4; ni++)
            bfr[ni] = load8(&Bs[(wn * 64 + ni * 16 + l15) * 32 + quad * 8]);
#pragma unroll
        for (int mi = 0; mi < 2; mi++)
#pragma unroll
            for (int ni = 0; ni < 4; ni++)
                acc[mi][ni] = __builtin_amdgcn_mfma_f32_16x16x32_bf16(af[mi], bfr[ni], acc[mi][ni], 0, 0, 0);
        __syncthreads();
    }

#pragma unroll
    for (int mi = 0; mi < 2; mi++)
#pragma unroll
        for (int ni = 0; ni < 4; ni++)
#pragma unroll
            for (int rg = 0; rg < 4; rg++) {
                int row = tm + wm * 32 + mi * 16 + quad * 4 + rg;
                int col = tn + wn * 64 + ni * 16 + l15;
                C[(size_t)row * N + col] = acc[mi][ni][rg];
            }
}

// ---------------- launch ----------------
extern "C" void kernel_launch(void* const* d_in, const int* in_sizes, int n_in,
                              void* d_out, int out_size, void* d_ws, size_t ws_size,
                              hipStream_t stream)
{
    const float* X  = (const float*)d_in[0];
    const float* Wq = (const float*)d_in[1];
    const float* Wk = (const float*)d_in[2];
    const float* Wv = (const float*)d_in[3];
    const float* Wo = (const float*)d_in[4];
    const int* tpos = (const int*)d_in[5];
    float* out = (float*)d_out;
    char* ws = (char*)d_ws;

    const size_t MB = (size_t)1 << 20;
    u16* Xb   = (u16*)(ws + 0);        // 8 MB; reused as Vt after gemm_qkv
    u16* WqB  = (u16*)(ws + 8 * MB);
    u16* WkB  = (u16*)(ws + 10 * MB);
    u16* WvB  = (u16*)(ws + 12 * MB);
    u16* WoB  = (u16*)(ws + 14 * MB);
    u16* Qraw = (u16*)(ws + 16 * MB);  // 8 MB; reused as AOut after rope
    u16* Kraw = (u16*)(ws + 24 * MB);
    u16* Vraw = (u16*)(ws + 32 * MB);
    u16* Qt   = (u16*)(ws + 40 * MB);
    u16* Kt   = (u16*)(ws + 48 * MB);
    u16* Vt   = Xb;
    u16* AOut = Qraw;

    cvt_all<<<dim3(1024, 8), 256, 0, stream>>>(X, Wq, Wk, Wv, Wo,
                                               Xb, WqB, WkB, WvB, WoB);

    gemm_qkv<<<dim3(32, 8, 3), 256, 0, stream>>>(Xb, WqB, WkB, WvB,
                                                 Qraw, Kraw, Vraw);
    rope_qk<<<8192, 256, 0, stream>>>(Qraw, Kraw, tpos, Qt, Kt);
    vtrans<<<dim3(32, 16, 2), 256, 0, stream>>>(Vraw, Vt);
    attn_kernel<<<dim3(512, 1, 1), 256, 0, stream>>>(Qt, Kt, Vt, AOut);
    gemm_o<<<dim3(64, 8), 256, 0, stream>>>(AOut, WoB, out);
}

// Round 4
// 185.203 us; speedup vs baseline: 1.0368x; 1.0368x over previous
//
#include <hip/hip_runtime.h>
#include <hip/hip_bf16.h>

#define D_MODEL 1024
#define NHEAD   16
#define HDIM    64
#define SEQQ    2048
#define NBATCH  2
#define MROWS   (NBATCH * SEQQ)   // 4096

typedef unsigned short u16;
typedef __attribute__((ext_vector_type(8))) short short8;   // 8 bf16 (4 VGPRs)
typedef __attribute__((ext_vector_type(4))) short bf16x4;   // 4 bf16 (2 VGPRs)
typedef __attribute__((ext_vector_type(4))) float floatx4;  // 4 fp32 acc

__device__ __forceinline__ u16 f2b(float f) {
    union { __hip_bfloat16 h; u16 u; } cv;
    cv.h = __float2bfloat16(f);
    return cv.u;
}
__device__ __forceinline__ float b2f(u16 u) {
    return __uint_as_float(((unsigned int)u) << 16);
}
__device__ __forceinline__ short8 load8(const u16* p) {
    return *reinterpret_cast<const short8*>(p);
}
__device__ __forceinline__ bf16x4 load4v(const u16* p) {
    return *reinterpret_cast<const bf16x4*>(p);
}
__device__ __forceinline__ unsigned pack2(float lo, float hi) {
    return ((unsigned)f2b(hi) << 16) | (unsigned)f2b(lo);
}
__device__ __forceinline__ void async_cp16(const void* g, void* l) {
    __builtin_amdgcn_global_load_lds(
        (const __attribute__((address_space(1))) void*)g,
        (__attribute__((address_space(3))) void*)l, 16, 0, 0);
}

// ---------------- fp32 -> bf16 convert: X (4 quarters) + 4 weights, one dispatch ----------------
__global__ void cvt_all(const float* __restrict__ X,
                        const float* __restrict__ w0, const float* __restrict__ w1,
                        const float* __restrict__ w2, const float* __restrict__ w3,
                        u16* __restrict__ xo,
                        u16* __restrict__ o0, u16* __restrict__ o1,
                        u16* __restrict__ o2, u16* __restrict__ o3) {
    const int z = blockIdx.y;
    const int n4 = (D_MODEL * D_MODEL) / 4;
    const float* in;
    u16* out;
    if (z < 4) { in = X + (size_t)z * n4 * 4;  out = xo + (size_t)z * n4 * 4; }
    else {
        in  = (z == 4) ? w0 : (z == 5) ? w1 : (z == 6) ? w2 : w3;
        out = (z == 4) ? o0 : (z == 5) ? o1 : (z == 6) ? o2 : o3;
    }
    const int i = blockIdx.x * 256 + threadIdx.x;
    float4 v = reinterpret_cast<const float4*>(in)[i];
    ushort4 o;
    o.x = f2b(v.x); o.y = f2b(v.y); o.z = f2b(v.z); o.w = f2b(v.w);
    reinterpret_cast<ushort4*>(out)[i] = o;
}

// ---------------- GEMM: C = A(MxK) * Bt(NxK)^T, m97-style 128x128 tile ----------------
__global__ __launch_bounds__(256) void gemm_qkv(
    const u16* __restrict__ A,
    const u16* __restrict__ B0, const u16* __restrict__ B1, const u16* __restrict__ B2,
    u16* __restrict__ C0, u16* __restrict__ C1, u16* __restrict__ C2)
{
    const int K = D_MODEL, N = D_MODEL;
    const u16* Bt = (blockIdx.z == 0) ? B0 : (blockIdx.z == 1 ? B1 : B2);
    u16*       Cp = (blockIdx.z == 0) ? C0 : (blockIdx.z == 1 ? C1 : C2);

    __shared__ __attribute__((aligned(16))) u16 As[128 * 32];
    __shared__ __attribute__((aligned(16))) u16 Bs[128 * 32];

    const int tid  = threadIdx.x;
    const int w    = tid >> 6;
    const int lane = tid & 63;
    const int l15  = lane & 15;
    const int quad = lane >> 4;
    const int wm   = w >> 1, wn = w & 1;
    const int tm   = blockIdx.x * 128, tn = blockIdx.y * 128;

    floatx4 acc[4][4];
#pragma unroll
    for (int i = 0; i < 4; i++)
#pragma unroll
        for (int j = 0; j < 4; j++) {
            floatx4 z = {0.f, 0.f, 0.f, 0.f};
            acc[i][j] = z;
        }

    const int srow = lane >> 2;
    const int scol = (lane & 3) * 8;

    for (int k0 = 0; k0 < K; k0 += 32) {
#pragma unroll
        for (int ch = w; ch < 8; ch += 4) {
            async_cp16(A  + (size_t)(tm + ch * 16 + srow) * K + k0 + scol, &As[ch * 512]);
            async_cp16(Bt + (size_t)(tn + ch * 16 + srow) * K + k0 + scol, &Bs[ch * 512]);
        }
        __syncthreads();

        short8 af[4], bfr[4];
#pragma unroll
        for (int mi = 0; mi < 4; mi++)
            af[mi] = load8(&As[(wm * 64 + mi * 16 + l15) * 32 + quad * 8]);
#pragma unroll
        for (int ni = 0; ni < 4; ni++)
            bfr[ni] = load8(&Bs[(wn * 64 + ni * 16 + l15) * 32 + quad * 8]);
#pragma unroll
        for (int mi = 0; mi < 4; mi++)
#pragma unroll
            for (int ni = 0; ni < 4; ni++)
                acc[mi][ni] = __builtin_amdgcn_mfma_f32_16x16x32_bf16(af[mi], bfr[ni], acc[mi][ni], 0, 0, 0);
        __syncthreads();
    }

#pragma unroll
    for (int mi = 0; mi < 4; mi++)
#pragma unroll
        for (int ni = 0; ni < 4; ni++)
#pragma unroll
            for (int rg = 0; rg < 4; rg++) {
                int row = tm + wm * 64 + mi * 16 + quad * 4 + rg;
                int col = tn + wn * 64 + ni * 16 + l15;
                Cp[(size_t)row * N + col] = f2b(acc[mi][ni][rg]);
            }
}

// ---------------- RoPE + [b,s,h,d] -> [b,h,s,d] transpose ----------------
// Q pre-scaled by (1/sqrt(HDIM)) * log2(e) so attn can use exp2 directly.
__global__ void rope_qk(const u16* __restrict__ Qraw, const u16* __restrict__ Kraw,
                        const int* __restrict__ pos, u16* __restrict__ Qt, u16* __restrict__ Kt)
{
    const int gid = blockIdx.x * 256 + threadIdx.x;
    const int j = gid & 31;
    const int s = (gid >> 5) & (SEQQ - 1);
    const int h = (gid >> 16) & (NHEAD - 1);
    const int b = gid >> 20;

    const float p   = (float)pos[s];
    const float inv = expf(-(float)j * (9.210340371976184f / 32.0f));
    float sn, cs;
    sincosf(p * inv, &sn, &cs);

    const size_t ioff = ((size_t)(b * SEQQ + s)) * D_MODEL + h * HDIM + 2 * j;
    const ushort2 qp = *reinterpret_cast<const ushort2*>(&Qraw[ioff]);
    const ushort2 kp = *reinterpret_cast<const ushort2*>(&Kraw[ioff]);
    const float qe = b2f(qp.x), qo = b2f(qp.y);
    const float ke = b2f(kp.x), ko = b2f(kp.y);

    const size_t ooff = (((size_t)(b * NHEAD + h)) * SEQQ + s) * HDIM + 2 * j;
    // 0.125 (1/sqrt(64)) * 1.4426950408889634 (log2 e)
    const float qs = 0.18033688011112042f;
    ushort2 qr;
    qr.x = f2b((qe * cs - qo * sn) * qs);
    qr.y = f2b((qe * sn + qo * cs) * qs);
    ushort2 kr;
    kr.x = f2b(ke * cs - ko * sn);
    kr.y = f2b(ke * sn + ko * cs);
    *reinterpret_cast<ushort2*>(&Qt[ooff]) = qr;
    *reinterpret_cast<ushort2*>(&Kt[ooff]) = kr;
}

// ---------------- V: [b,s,h*d] -> [b,h,d,s] transpose ----------------
__global__ __launch_bounds__(256) void vtrans(const u16* __restrict__ Vraw, u16* __restrict__ Vt)
{
    __shared__ u16 tile[64][65];
    const int s0 = blockIdx.x * 64, h = blockIdx.y, b = blockIdx.z;
    const int t = threadIdx.x;
#pragma unroll
    for (int i = 0; i < 16; i++) {
        int idx = t + i * 256;
        int sl = idx >> 6, dl = idx & 63;
        tile[sl][dl] = Vraw[((size_t)(b * SEQQ + s0 + sl)) * D_MODEL + h * HDIM + dl];
    }
    __syncthreads();
#pragma unroll
    for (int i = 0; i < 16; i++) {
        int idx = t + i * 256;
        int dl = idx >> 6, sl = idx & 63;
        Vt[(((size_t)(b * NHEAD + h)) * HDIM + dl) * SEQQ + s0 + sl] = tile[sl][dl];
    }
}

// ---------------- causal flash attention v12: occupancy restructure ----------------
// v11 post-mortem: all pipes <33% busy, 2 blocks/CU (48KB LDS), 2 waves/SIMD
// -> latency-bound. 3360 cy/tile-iter/CU vs ~700 cy MFMA floor.
// v12: one 64-row q-sub-block per block (no phase loop), 1024 blocks,
// DOUBLE-buffered K/V (32 KB LDS) -> 4-5 blocks/CU resident = 16-20 waves/CU
// = 4-5 waves/SIMD. Prefetch distance 1 is enough (tile compute ~1500 cy >>
// L2 latency ~300 cy): per iter = vmcnt(0), barrier, stage(t+1), compute(t).
// stage(t+1) is buffer-safe: it follows the barrier that follows compute(t-1),
// which was the last reader of buf[(t+1)&1].
// Static balance map (assumes round-robin block->XCD->CU fill; perf-only
// heuristic): CU c hosts u = c (mod 32) -> m in {m0, m0+8, m0+16, m0+24};
// qsub = g(m) = {31-m, m-8, 39-m, m-16} makes every CU quadruple sum to
// exactly 66 tile-iters, longest blocks dispatched first. All 4 blocks of a
// CU share one (b,h) column; each XCD owns 4 columns (3 MB < 4 MB L2).
__global__ __launch_bounds__(256, 4) void attn_kernel(
    const u16* __restrict__ Qt, const u16* __restrict__ Kt, const u16* __restrict__ Vt,
    u16* __restrict__ Out)
{
    const int bid = blockIdx.x;
    const int xcd = bid & 7;
    const int u   = bid >> 3;               // 0..127 within XCD
    const int col = xcd * 4 + (u & 3);      // (b,h) column 0..31, 4 per XCD
    const int m   = u >> 2;                 // 0..31
    int qsub;
    if      (m < 8)  qsub = 31 - m;
    else if (m < 16) qsub = m - 8;
    else if (m < 24) qsub = 39 - m;
    else             qsub = m - 16;
    const int h = col & (NHEAD - 1), b = col >> 4;

    const int tid = threadIdx.x, w = tid >> 6, lane = tid & 63;
    const int l15 = lane & 15, quad = lane >> 4;
    const size_t bh = (size_t)(b * NHEAD + h);
    const u16* Qh = Qt + bh * SEQQ * HDIM;
    const u16* Kh = Kt + bh * SEQQ * HDIM;
    const u16* Vh = Vt + bh * HDIM * SEQQ;   // [d][s]

    __shared__ __attribute__((aligned(16))) u16 Ks[2][64 * 64];   // 16 KB
    __shared__ __attribute__((aligned(16))) u16 Vs[2][64 * 64];   // 16 KB

    short8 ones;
#pragma unroll
    for (int i = 0; i < 8; i++) ones[i] = (short)0x3F80;  // bf16 1.0

    // staging: each of 4 waves stages 2 K-chunks + 2 V-chunks (1 KB each)
    const int rr  = lane >> 3;                 // 0..7
    const int swz = ((lane & 7) ^ rr) * 8;     // XOR-swizzled col offset (u16)
    auto stage = [&](int buf, int tt) {
        const int k0s = tt * 64;
        async_cp16(Kh + (size_t)(k0s + w * 8 + rr) * HDIM + swz,       &Ks[buf][w * 512]);
        async_cp16(Kh + (size_t)(k0s + (w + 4) * 8 + rr) * HDIM + swz, &Ks[buf][(w + 4) * 512]);
        async_cp16(Vh + (size_t)(w * 8 + rr) * SEQQ + k0s + swz,       &Vs[buf][w * 512]);
        async_cp16(Vh + (size_t)((w + 4) * 8 + rr) * SEQQ + k0s + swz, &Vs[buf][(w + 4) * 512]);
    };

    const int s7  = l15 & 7;
    const int sw1 = ((quad)     ^ s7) * 8;     // K dims chunk 0..31
    const int sw2 = ((quad + 4) ^ s7) * 8;     // K dims chunk 32..63
    // V b64 element offsets for permuted PV k-slots (chunk*8 + (quad&1)*4):
    const int vo0 = (((quad >> 1)    ) ^ s7) * 8 + (quad & 1) * 4;  // keys  4*quad..
    const int vo1 = (((quad >> 1) + 2) ^ s7) * 8 + (quad & 1) * 4;  // keys 16+4*quad..
    const int vo2 = (((quad >> 1) + 4) ^ s7) * 8 + (quad & 1) * 4;  // keys 32+4*quad..
    const int vo3 = (((quad >> 1) + 6) ^ s7) * 8 + (quad & 1) * 4;  // keys 48+4*quad..

    const int q0w   = qsub * 64 + w * 16;      // this wave's 16 q-rows
    const int tmaxp = qsub;                    // diag tile, same for all 4 waves

    // Q fragment loads FIRST (drained together with stage(0) by first vmcnt(0))
    short8 qf[2];
#pragma unroll
    for (int kk = 0; kk < 2; kk++)
        qf[kk] = load8(&Qh[(size_t)(q0w + l15) * HDIM + kk * 32 + quad * 8]);

    floatx4 O[4];
    floatx4 l_acc = {0.f, 0.f, 0.f, 0.f};
#pragma unroll
    for (int c = 0; c < 4; c++) { floatx4 z = {0.f, 0.f, 0.f, 0.f}; O[c] = z; }

    stage(0, 0);

    for (int t = 0; t <= tmaxp; ++t) {
        // stage(t) (4 DMAs, issued one full tile-compute ago) must be complete
        asm volatile("s_waitcnt vmcnt(0)" ::: "memory");
        __builtin_amdgcn_s_barrier();
        if (t < tmaxp) stage((t + 1) & 1, t + 1);   // prefetch distance 1

        const u16* KsB = &Ks[t & 1][0];
        const u16* VsB = &Vs[t & 1][0];
        const int k0 = t * 64;

        // S^T[c]: rows = key_local (c*16 + quad*4 + r), cols = q (l15)
        floatx4 S[4];
#pragma unroll
        for (int c = 0; c < 4; c++) {
            const int rowb = (c * 16 + l15) * 64;
            floatx4 z = {0.f, 0.f, 0.f, 0.f};
            S[c] = __builtin_amdgcn_mfma_f32_16x16x32_bf16(load8(&KsB[rowb + sw1]), qf[0], z,    0, 0, 0);
            S[c] = __builtin_amdgcn_mfma_f32_16x16x32_bf16(load8(&KsB[rowb + sw2]), qf[1], S[c], 0, 0, 0);
        }

        if (t == tmaxp) {
            const int q = q0w + l15;
#pragma unroll
            for (int c = 0; c < 4; c++)
#pragma unroll
                for (int r = 0; r < 4; r++)
                    if (k0 + c * 16 + quad * 4 + r > q) S[c][r] = -1e30f;
        }

#pragma unroll
        for (int c = 0; c < 4; c++)
#pragma unroll
            for (int r = 0; r < 4; r++)
                S[c][r] = __builtin_amdgcn_exp2f(S[c][r]);

        // ---- pack P into PV A-fragments (lane-local, permuted k-slots) ----
        union { short8 v; unsigned u[4]; } pf0, pf1;
        pf0.u[0] = pack2(S[0][0], S[0][1]);
        pf0.u[1] = pack2(S[0][2], S[0][3]);
        pf0.u[2] = pack2(S[1][0], S[1][1]);
        pf0.u[3] = pack2(S[1][2], S[1][3]);
        pf1.u[0] = pack2(S[2][0], S[2][1]);
        pf1.u[1] = pack2(S[2][2], S[2][3]);
        pf1.u[2] = pack2(S[3][0], S[3][1]);
        pf1.u[3] = pack2(S[3][2], S[3][3]);

        l_acc = __builtin_amdgcn_mfma_f32_16x16x32_bf16(pf0.v, ones, l_acc, 0, 0, 0);
        l_acc = __builtin_amdgcn_mfma_f32_16x16x32_bf16(pf1.v, ones, l_acc, 0, 0, 0);

#pragma unroll
        for (int c2 = 0; c2 < 4; c2++) {
            const int rowb = (c2 * 16 + l15) * 64;
            bf16x4 a0 = load4v(&VsB[rowb + vo0]);
            bf16x4 a1 = load4v(&VsB[rowb + vo1]);
            bf16x4 a2 = load4v(&VsB[rowb + vo2]);
            bf16x4 a3 = load4v(&VsB[rowb + vo3]);
            short8 v0 = __builtin_shufflevector(a0, a1, 0, 1, 2, 3, 4, 5, 6, 7);
            short8 v1 = __builtin_shufflevector(a2, a3, 0, 1, 2, 3, 4, 5, 6, 7);
            O[c2] = __builtin_amdgcn_mfma_f32_16x16x32_bf16(pf0.v, v0, O[c2], 0, 0, 0);
            O[c2] = __builtin_amdgcn_mfma_f32_16x16x32_bf16(pf1.v, v1, O[c2], 0, 0, 0);
        }
    }

    float inv_l[4];
#pragma unroll
    for (int r = 0; r < 4; r++) inv_l[r] = 1.0f / l_acc[r];

#pragma unroll
    for (int c2 = 0; c2 < 4; c2++)
#pragma unroll
        for (int r = 0; r < 4; r++) {
            const int q    = q0w + quad * 4 + r;
            const int colo = h * HDIM + c2 * 16 + l15;
            Out[(size_t)(b * SEQQ + q) * D_MODEL + colo] = f2b(O[c2][r] * inv_l[r]);
        }
}

// ---------------- o-proj GEMM: 64x128 tile (512 blocks -> 2/CU backfill) ----------------
__global__ __launch_bounds__(256) void gemm_o(
    const u16* __restrict__ A, const u16* __restrict__ Bt, float* __restrict__ C)
{
    const int K = D_MODEL, N = D_MODEL;
    __shared__ __attribute__((aligned(16))) u16 As[64 * 32];
    __shared__ __attribute__((aligned(16))) u16 Bs[128 * 32];

    const int tid  = threadIdx.x;
    const int w    = tid >> 6;
    const int lane = tid & 63;
    const int l15  = lane & 15;
    const int quad = lane >> 4;
    const int wm   = w >> 1, wn = w & 1;
    const int tm   = blockIdx.x * 64, tn = blockIdx.y * 128;

    floatx4 acc[2][4];
#pragma unroll
    for (int i = 0; i < 2; i++)
#pragma unroll
        for (int j = 0; j < 4; j++) {
            floatx4 z = {0.f, 0.f, 0.f, 0.f};
            acc[i][j] = z;
        }

    const int srow = lane >> 2;
    const int scol = (lane & 3) * 8;

    for (int k0 = 0; k0 < K; k0 += 32) {
#pragma unroll
        for (int ch = w; ch < 12; ch += 4) {
            if (ch < 4) async_cp16(A  + (size_t)(tm + ch * 16 + srow) * K + k0 + scol, &As[ch * 512]);
            else        async_cp16(Bt + (size_t)(tn + (ch - 4) * 16 + srow) * K + k0 + scol, &Bs[(ch - 4) * 512]);
        }
        __syncthreads();

        short8 af[2], bfr[4];
#pragma unroll
        for (int mi = 0; mi < 2; mi++)
            af[mi] = load8(&As[(wm * 32 + mi * 16 + l15) * 32 + quad * 8]);
#pragma unroll
        for (int ni = 0; ni < 4; ni++)
            bfr[ni] = load8(&Bs[(wn * 64 + ni * 16 + l15) * 32 + quad * 8]);
#pragma unroll
        for (int mi = 0; mi < 2; mi++)
#pragma unroll
            for (int ni = 0; ni < 4; ni++)
                acc[mi][ni] = __builtin_amdgcn_mfma_f32_16x16x32_bf16(af[mi], bfr[ni], acc[mi][ni], 0, 0, 0);
        __syncthreads();
    }

#pragma unroll
    for (int mi = 0; mi < 2; mi++)
#pragma unroll
        for (int ni = 0; ni < 4; ni++)
#pragma unroll
            for (int rg = 0; rg < 4; rg++) {
                int row = tm + wm * 32 + mi * 16 + quad * 4 + rg;
                int col = tn + wn * 64 + ni * 16 + l15;
                C[(size_t)row * N + col] = acc[mi][ni][rg];
            }
}

// ---------------- launch ----------------
extern "C" void kernel_launch(void* const* d_in, const int* in_sizes, int n_in,
                              void* d_out, int out_size, void* d_ws, size_t ws_size,
                              hipStream_t stream)
{
    const float* X  = (const float*)d_in[0];
    const float* Wq = (const float*)d_in[1];
    const float* Wk = (const float*)d_in[2];
    const float* Wv = (const float*)d_in[3];
    const float* Wo = (const float*)d_in[4];
    const int* tpos = (const int*)d_in[5];
    float* out = (float*)d_out;
    char* ws = (char*)d_ws;

    const size_t MB = (size_t)1 << 20;
    u16* Xb   = (u16*)(ws + 0);        // 8 MB; reused as Vt after gemm_qkv
    u16* WqB  = (u16*)(ws + 8 * MB);
    u16* WkB  = (u16*)(ws + 10 * MB);
    u16* WvB  = (u16*)(ws + 12 * MB);
    u16* WoB  = (u16*)(ws + 14 * MB);
    u16* Qraw = (u16*)(ws + 16 * MB);  // 8 MB; reused as AOut after rope
    u16* Kraw = (u16*)(ws + 24 * MB);
    u16* Vraw = (u16*)(ws + 32 * MB);
    u16* Qt   = (u16*)(ws + 40 * MB);
    u16* Kt   = (u16*)(ws + 48 * MB);
    u16* Vt   = Xb;
    u16* AOut = Qraw;

    cvt_all<<<dim3(1024, 8), 256, 0, stream>>>(X, Wq, Wk, Wv, Wo,
                                               Xb, WqB, WkB, WvB, WoB);

    gemm_qkv<<<dim3(32, 8, 3), 256, 0, stream>>>(Xb, WqB, WkB, WvB,
                                                 Qraw, Kraw, Vraw);
    rope_qk<<<8192, 256, 0, stream>>>(Qraw, Kraw, tpos, Qt, Kt);
    vtrans<<<dim3(32, 16, 2), 256, 0, stream>>>(Vraw, Vt);
    attn_kernel<<<dim3(1024, 1, 1), 256, 0, stream>>>(Qt, Kt, Vt, AOut);
    gemm_o<<<dim3(64, 8), 256, 0, stream>>>(AOut, WoB, out);
}